// Round 1
// baseline (1158.669 us; speedup 1.0000x reference)
//
#include <hip/hip_runtime.h>
#include <math.h>

#define BATCH 4096
#define SEQ   50
#define DIM   768
#define UDIM  768
#define QDIM  200

// ---------------------------------------------------------------------------
// Tiled fp32 GEMM:  out[B, N] = act( A[B, K] @ Wt[N, K]^T + bias[N] )
// 64x64 tile per block, 256 threads, 4x4 accumulators per thread,
// K staged in 16-wide chunks through LDS (pad to 68 floats: keeps 16B
// alignment for b128 reads, bank aliasing <= 2-way which is free).
// ACT: 0 = relu, 1 = tanh
// ---------------------------------------------------------------------------
template<int N, int K, int ACT>
__global__ __launch_bounds__(256) void pa_gemm_kernel(
    const float* __restrict__ A,
    const float* __restrict__ Wt,
    const float* __restrict__ bias,
    float* __restrict__ out)
{
    __shared__ float As[16][68];
    __shared__ float Bs[16][68];

    const int tid = threadIdx.x;
    const int tx  = tid & 15;        // 0..15  (cols)
    const int ty  = tid >> 4;        // 0..15  (rows)
    const int bm  = blockIdx.y * 64; // batch-row tile
    const int bn  = blockIdx.x * 64; // output-col tile
    const int lm  = tid >> 2;        // 0..63  load row/col
    const int lk  = (tid & 3) << 2;  // 0,4,8,12 load k offset

    float acc[4][4];
    #pragma unroll
    for (int i = 0; i < 4; i++)
        #pragma unroll
        for (int j = 0; j < 4; j++) acc[i][j] = 0.f;

    const int nk = (K + 15) / 16;
    for (int kc = 0; kc < nk; kc++) {
        const int k0 = kc * 16;
        const int ak = k0 + lk;

        float4 a4 = make_float4(0.f, 0.f, 0.f, 0.f);
        if (ak < K)  // K % 4 == 0 and ak % 4 == 0 -> full float4 in-bounds
            a4 = *(const float4*)&A[(size_t)(bm + lm) * K + ak];

        float4 b4 = make_float4(0.f, 0.f, 0.f, 0.f);
        const int nn = bn + lm;
        if (nn < N && ak < K)
            b4 = *(const float4*)&Wt[(size_t)nn * K + ak];

        __syncthreads();   // protect LDS from previous iteration's readers
        As[lk + 0][lm] = a4.x; As[lk + 1][lm] = a4.y;
        As[lk + 2][lm] = a4.z; As[lk + 3][lm] = a4.w;
        Bs[lk + 0][lm] = b4.x; Bs[lk + 1][lm] = b4.y;
        Bs[lk + 2][lm] = b4.z; Bs[lk + 3][lm] = b4.w;
        __syncthreads();

        #pragma unroll
        for (int k = 0; k < 16; k++) {
            float4 av = *(const float4*)&As[k][ty << 2];
            float4 bv = *(const float4*)&Bs[k][tx << 2];
            float am[4] = {av.x, av.y, av.z, av.w};
            float bb[4] = {bv.x, bv.y, bv.z, bv.w};
            #pragma unroll
            for (int i = 0; i < 4; i++)
                #pragma unroll
                for (int j = 0; j < 4; j++)
                    acc[i][j] = fmaf(am[i], bb[j], acc[i][j]);
        }
    }

    const int col = bn + (tx << 2);
    if (col < N) {   // N % 4 == 0 -> whole float4 valid when col < N
        #pragma unroll
        for (int i = 0; i < 4; i++) {
            const int row = bm + (ty << 2) + i;
            float v[4];
            #pragma unroll
            for (int j = 0; j < 4; j++) {
                float x = acc[i][j] + bias[col + j];
                v[j] = (ACT == 0) ? fmaxf(x, 0.f) : tanhf(x);
            }
            float4 r = make_float4(v[0], v[1], v[2], v[3]);
            *(float4*)&out[(size_t)row * N + col] = r;
        }
    }
}

// ---------------------------------------------------------------------------
// Attention kernel: one block per batch row b.
//  phase 1: stage w[b,:] (768 f32) in LDS
//  phase 2: 4 waves compute the 50 scores s = dot(c[b,s,:], w[b,:])
//  phase 3: wave 0 does the 50-wide softmax in-register
//  phase 4: out[b,s,d] = c[b,s,d] * attn[s]   (c re-read is L3-hot)
// ---------------------------------------------------------------------------
__global__ __launch_bounds__(256) void pa_attn_kernel(
    const float* __restrict__ c,
    const float* __restrict__ w,
    float* __restrict__ out)
{
    __shared__ float wv[DIM];
    __shared__ float sc[64];

    const int b   = blockIdx.x;
    const int tid = threadIdx.x;
    const int wave = tid >> 6;
    const int lane = tid & 63;

    const float* cb = c + (size_t)b * (SEQ * DIM);

    // stage w[b]
    {
        const float4* w4  = (const float4*)(w + (size_t)b * DIM);
        float4*       wv4 = (float4*)wv;
        if (tid < DIM / 4) wv4[tid] = w4[tid];   // 192 float4s, 256 threads
    }
    __syncthreads();

    // scores
    for (int s = wave; s < SEQ; s += 4) {
        const float* row = cb + s * DIM;
        float acc = 0.f;
        #pragma unroll
        for (int p = 0; p < 3; p++) {
            const int d = p * 256 + (lane << 2);
            float4 cv = *(const float4*)&row[d];
            acc = fmaf(cv.x, wv[d + 0], acc);
            acc = fmaf(cv.y, wv[d + 1], acc);
            acc = fmaf(cv.z, wv[d + 2], acc);
            acc = fmaf(cv.w, wv[d + 3], acc);
        }
        #pragma unroll
        for (int off = 32; off > 0; off >>= 1)
            acc += __shfl_down(acc, off, 64);
        if (lane == 0) sc[s] = acc;
    }
    __syncthreads();

    // softmax over S=50 (wave 0 only)
    if (wave == 0) {
        float x = (lane < SEQ) ? sc[lane] : -INFINITY;
        float m = x;
        #pragma unroll
        for (int off = 32; off > 0; off >>= 1)
            m = fmaxf(m, __shfl_down(m, off, 64));
        m = __shfl(m, 0, 64);
        float e = (lane < SEQ) ? expf(x - m) : 0.f;
        float sum = e;
        #pragma unroll
        for (int off = 32; off > 0; off >>= 1)
            sum += __shfl_down(sum, off, 64);
        sum = __shfl(sum, 0, 64);
        const float inv = 1.f / sum;
        if (lane < SEQ) sc[lane] = e * inv;
    }
    __syncthreads();

    // scale pass: out = c * attn  (float4, coalesced)
    const float4* c4 = (const float4*)cb;
    float4*       o4 = (float4*)(out + (size_t)b * (SEQ * DIM));
    const int nv = SEQ * DIM / 4;       // 9600 float4 per batch row
    for (int i = tid; i < nv; i += 256) {
        const int s = i / (DIM / 4);    // 192 float4 per seq row
        const float a = sc[s];
        float4 v = c4[i];
        v.x *= a; v.y *= a; v.z *= a; v.w *= a;
        o4[i] = v;
    }
}

extern "C" void kernel_launch(void* const* d_in, const int* in_sizes, int n_in,
                              void* d_out, int out_size, void* d_ws, size_t ws_size,
                              hipStream_t stream) {
    const float* c  = (const float*)d_in[0];   // [B, S, D]
    const float* ue = (const float*)d_in[1];   // [B, U]
    const float* W1 = (const float*)d_in[2];   // [Q, U]
    const float* b1 = (const float*)d_in[3];   // [Q]
    const float* W2 = (const float*)d_in[4];   // [D, Q]
    const float* b2 = (const float*)d_in[5];   // [D]
    float* out = (float*)d_out;

    float* q = (float*)d_ws;                   // [B, Q]  = 3.28 MB
    float* w = q + (size_t)BATCH * QDIM;       // [B, D]  = 12.6 MB

    // q = relu(ue @ W1^T + b1):  M=4096, N=200, K=768
    dim3 g1((QDIM + 63) / 64, BATCH / 64);
    pa_gemm_kernel<QDIM, UDIM, 0><<<g1, 256, 0, stream>>>(ue, W1, b1, q);

    // w = tanh(q @ W2^T + b2):   M=4096, N=768, K=200
    dim3 g2(DIM / 64, BATCH / 64);
    pa_gemm_kernel<DIM, QDIM, 1><<<g2, 256, 0, stream>>>(q, W2, b2, w);

    // attention + scale
    pa_attn_kernel<<<BATCH, 256, 0, stream>>>(c, w, out);
}